// Round 10
// baseline (549.688 us; speedup 1.0000x reference)
//
#include <hip/hip_runtime.h>

#define N_NODES 100000
#define N_EDGES 1250000
#define FEAT 64
#define N_GRAPHS 64
#define SLOT_MAIN 16
#define SLOT_OVF 32
#define MAXDEG 48     // SLOT_MAIN + SLOT_OVF
#define NRANGE 8      // dst ranges, one per XCD (blockIdx%8 -> XCD round-robin)
#define RANGE_SZ (N_NODES / NRANGE)  // 12500
#define GRP 64        // nodes per wave-group (lane=node MLP phase)
#define PITCH 65      // LDS pitch: conflict-free row AND column b32 access
#define N_GROUPS ((N_NODES + GRP - 1) / GRP)  // 1563

// ---------------------------------------------------------------------------
// Transpose the four 64x64 weight matrices: WT[m][j][k] = W_m[k][j]
// (lane=node MLP wants W^T rows contiguous for wave-uniform s_loads)
// ---------------------------------------------------------------------------
__global__ void transpose4_kernel(const float* __restrict__ W1_0,
                                  const float* __restrict__ W2_0,
                                  const float* __restrict__ W1_1,
                                  const float* __restrict__ W2_1,
                                  float* __restrict__ WT) {
  const int m = blockIdx.x >> 6;   // 0..3
  const int j = blockIdx.x & 63;
  const int k = threadIdx.x;
  const float* W = (m == 0) ? W1_0 : (m == 1) ? W2_0 : (m == 2) ? W1_1 : W2_1;
  WT[(m * FEAT + j) * FEAT + k] = W[k * FEAT + j];
}

// ---------------------------------------------------------------------------
// Build per-destination edge buckets, XCD-affine (round-6 design).
// ---------------------------------------------------------------------------
__global__ void hist_place_kernel(const int* __restrict__ src,
                                  const int* __restrict__ dst,
                                  int* __restrict__ deg,
                                  int* __restrict__ slots16,
                                  int* __restrict__ slots_ovf) {
  const int r   = blockIdx.x & (NRANGE - 1);
  const int ch  = blockIdx.x >> 3;
  const int nch = gridDim.x >> 3;
  const int lo  = r * RANGE_SZ;
  const int eper = (N_EDGES + nch - 1) / nch;
  const int e0 = ch * eper;
  const int e1 = min(e0 + eper, N_EDGES);
  for (int e = e0 + (int)threadIdx.x; e < e1; e += blockDim.x) {
    const int d = dst[e];
    if ((unsigned)(d - lo) < (unsigned)RANGE_SZ) {
      const int s = src[e];
      const int pos = atomicAdd(&deg[d], 1);
      if (pos < SLOT_MAIN)   slots16[(d << 4) + pos] = s;
      else if (pos < MAXDEG) slots_ovf[d * SLOT_OVF + (pos - SLOT_MAIN)] = s;
    }
  }
}

// ---------------------------------------------------------------------------
// Fused GIN layer, wave-private 64-node groups.
//  phase G (lane=feat): round-8 paired gather (34 loads in flight) -> LDS rows
//  phase M (lane=node): node's row in 64 VGPRs; W^T rows are wave-uniform ->
//    SGPR operands; 64 fma/node/layer, ZERO readlanes. h1/h2 via same LDS.
//  phase O (lane=feat): coalesced store or sorted-batch pooling.
// No __syncthreads anywhere: LDS region is wave-private, same-wave ds
// ordering handled by compiler lgkmcnt.
// ---------------------------------------------------------------------------
template <bool POOL>
__global__ __launch_bounds__(256) void gin_layer_kernel(
    const float* __restrict__ hin,
    const int* __restrict__ deg,
    const int* __restrict__ slots16,
    const int* __restrict__ slots_ovf,
    const float* __restrict__ W1T, const float* __restrict__ b1,
    const float* __restrict__ W2T, const float* __restrict__ b2,
    float* __restrict__ hout,
    const int* __restrict__ batch,
    float* __restrict__ sums) {
  __shared__ float lds_all[4 * GRP * PITCH];   // 66.56 KB -> 2 blocks/CU
  const int lane = threadIdx.x & 63;
  const int w    = threadIdx.x >> 6;
  float* __restrict__ lds = lds_all + w * (GRP * PITCH);

  int wg = blockIdx.x * 4 + w;
  wg = __builtin_amdgcn_readfirstlane(wg);
  const int nwg = gridDim.x * 4;

  const float r0 = hin[lane];   // row 0 (sentinel row for zero-filled slots)

  for (int grp = wg; grp < N_GROUPS; grp += nwg) {
    const int nbase = grp * GRP;

    // ---- phase G: gather 32 node pairs into LDS rows ----
    for (int i = 0; i < GRP / 2; ++i) {
      const int nA = nbase + 2 * i;
      const int nB = nA + 1;
      if (nA >= N_NODES) {              // whole-pair tail skip (N even)
        lds[(2 * i) * PITCH + lane] = 0.0f;
        lds[(2 * i + 1) * PITCH + lane] = 0.0f;
        continue;
      }
      const int cA  = min(deg[nA], MAXDEG);
      const int cB  = min(deg[nB], MAXDEG);
      const int cmA = min(cA, SLOT_MAIN);
      const int cmB = min(cB, SLOT_MAIN);

      const int* slA = slots16 + (nA << 4);
      const int* slB = slots16 + (nB << 4);
      int sA[SLOT_MAIN], sB[SLOT_MAIN];
#pragma unroll
      for (int ii = 0; ii < SLOT_MAIN; ++ii) sA[ii] = slA[ii];
#pragma unroll
      for (int ii = 0; ii < SLOT_MAIN; ++ii) sB[ii] = slB[ii];

      float aA = hin[((unsigned)nA << 6) + lane];
      float aB = hin[((unsigned)nB << 6) + lane];
      float vA[SLOT_MAIN], vB[SLOT_MAIN];
#pragma unroll
      for (int ii = 0; ii < SLOT_MAIN; ++ii) vA[ii] = hin[((unsigned)sA[ii] << 6) + lane];
#pragma unroll
      for (int ii = 0; ii < SLOT_MAIN; ++ii) vB[ii] = hin[((unsigned)sB[ii] << 6) + lane];

      // unconditional tree-sum + sentinel correction (slots pre-zeroed)
#pragma unroll
      for (int st = 1; st < SLOT_MAIN; st <<= 1)
#pragma unroll
        for (int ii = 0; ii < SLOT_MAIN; ii += (st << 1)) {
          vA[ii] += vA[ii + st];
          vB[ii] += vB[ii + st];
        }
      aA += vA[0];
      aB += vB[0];
      aA = fmaf((float)(cmA - SLOT_MAIN), r0, aA);
      aB = fmaf((float)(cmB - SLOT_MAIN), r0, aB);

      if (cA > SLOT_MAIN) {             // uniform branch, ~12% of nodes
        const int* so = slots_ovf + (size_t)nA * SLOT_OVF;
        for (int ii = SLOT_MAIN; ii < cA; ++ii)
          aA += hin[((unsigned)so[ii - SLOT_MAIN] << 6) + lane];
      }
      if (cB > SLOT_MAIN) {
        const int* so = slots_ovf + (size_t)nB * SLOT_OVF;
        for (int ii = SLOT_MAIN; ii < cB; ++ii)
          aB += hin[((unsigned)so[ii - SLOT_MAIN] << 6) + lane];
      }

      lds[(2 * i) * PITCH + lane] = aA;
      lds[(2 * i + 1) * PITCH + lane] = aB;
    }

    // ---- phase M: two linears, lane = node ----
    {
      float ar[FEAT];
#pragma unroll
      for (int k = 0; k < FEAT; ++k) ar[k] = lds[lane * PITCH + k];
#pragma unroll 2
      for (int j = 0; j < FEAT; j += 2) {
        const float* __restrict__ w0 = W1T + j * FEAT;        // wave-uniform
        const float* __restrict__ w1r = W1T + (j + 1) * FEAT;
        float acc0 = b1[j], acc1 = b1[j + 1];
#pragma unroll
        for (int k = 0; k < FEAT; ++k) {
          acc0 = fmaf(ar[k], w0[k], acc0);
          acc1 = fmaf(ar[k], w1r[k], acc1);
        }
        lds[lane * PITCH + j]     = fmaxf(acc0, 0.0f);
        lds[lane * PITCH + j + 1] = fmaxf(acc1, 0.0f);
      }
#pragma unroll
      for (int k = 0; k < FEAT; ++k) ar[k] = lds[lane * PITCH + k];
#pragma unroll 2
      for (int j = 0; j < FEAT; j += 2) {
        const float* __restrict__ w0 = W2T + j * FEAT;
        const float* __restrict__ w1r = W2T + (j + 1) * FEAT;
        float acc0 = b2[j], acc1 = b2[j + 1];
#pragma unroll
        for (int k = 0; k < FEAT; ++k) {
          acc0 = fmaf(ar[k], w0[k], acc0);
          acc1 = fmaf(ar[k], w1r[k], acc1);
        }
        lds[lane * PITCH + j]     = fmaxf(acc0, 0.0f);
        lds[lane * PITCH + j + 1] = fmaxf(acc1, 0.0f);
      }
    }

    // ---- phase O: output (lane = feat) ----
    if (POOL) {
      int curg = -1;
      float gacc = 0.0f;
      for (int i = 0; i < GRP; ++i) {
        const int n = nbase + i;
        if (n >= N_NODES) break;
        const float hv = lds[i * PITCH + lane];
        const int g = batch[n];               // wave-uniform
        if (g != curg) {
          if (curg >= 0) atomicAdd(&sums[curg * FEAT + lane], gacc);
          curg = g; gacc = 0.0f;
        }
        gacc += hv;
      }
      if (curg >= 0) atomicAdd(&sums[curg * FEAT + lane], gacc);
    } else {
      for (int i = 0; i < GRP; ++i) {
        const int n = nbase + i;
        if (n >= N_NODES) break;
        hout[((unsigned)n << 6) + lane] = lds[i * PITCH + lane];
      }
    }
  }
}

// ---------------------------------------------------------------------------
// out[g] = dot(sums[g,:], fcW) / cnt[g] + fcb; cnt via binary search on the
// sorted batch array.
// ---------------------------------------------------------------------------
__device__ __forceinline__ int lower_bound_dev(const int* __restrict__ a,
                                               int n, int key) {
  int lo = 0, hi = n;
  while (lo < hi) {
    const int mid = (lo + hi) >> 1;
    if (a[mid] < key) lo = mid + 1; else hi = mid;
  }
  return lo;
}

__global__ void finish_kernel(const float* __restrict__ sums,
                              const int* __restrict__ batch,
                              const float* __restrict__ fcW,
                              const float* __restrict__ fcb,
                              float* __restrict__ out) {
  const int g = blockIdx.x;
  const int lane = threadIdx.x;

  int cnt = 0;
  if (lane == 0) {
    const int lo = lower_bound_dev(batch, N_NODES, g);
    const int hi = lower_bound_dev(batch, N_NODES, g + 1);
    cnt = hi - lo;
  }
  cnt = __shfl(cnt, 0);

  float v = sums[g * FEAT + lane] * fcW[lane];
#pragma unroll
  for (int off = 32; off > 0; off >>= 1) v += __shfl_down(v, off);
  if (lane == 0) out[g] = v / fmaxf((float)cnt, 1.0f) + fcb[0];
}

extern "C" void kernel_launch(void* const* d_in, const int* in_sizes, int n_in,
                              void* d_out, int out_size, void* d_ws, size_t ws_size,
                              hipStream_t stream) {
  const float* x     = (const float*)d_in[0];
  const int*   ei    = (const int*)d_in[1];
  const int*   batch = (const int*)d_in[2];
  const float* W1_0  = (const float*)d_in[3];
  const float* b1_0  = (const float*)d_in[4];
  const float* W2_0  = (const float*)d_in[5];
  const float* b2_0  = (const float*)d_in[6];
  const float* W1_1  = (const float*)d_in[7];
  const float* b1_1  = (const float*)d_in[8];
  const float* W2_1  = (const float*)d_in[9];
  const float* b2_1  = (const float*)d_in[10];
  const float* fcW   = (const float*)d_in[11];
  const float* fcb   = (const float*)d_in[12];
  float* out = (float*)d_out;

  const int* src = ei;            // edge_index[0]
  const int* dst = ei + N_EDGES;  // edge_index[1]

  // workspace layout: [deg | sums | slots16 | slots_ovf | h1 | WT]
  int*   deg       = (int*)d_ws;                            // N_NODES
  float* sums      = (float*)(deg + N_NODES);               // N_GRAPHS*FEAT
  int*   slots16   = (int*)(sums + N_GRAPHS * FEAT);        // N_NODES*16
  int*   slots_ovf = slots16 + (size_t)N_NODES * SLOT_MAIN; // N_NODES*32
  float* h1        = (float*)(slots_ovf + (size_t)N_NODES * SLOT_OVF); // N_NODES*FEAT
  float* wt        = h1 + (size_t)N_NODES * FEAT;           // 4*FEAT*FEAT
  float* W1_0T = wt;
  float* W2_0T = wt + FEAT * FEAT;
  float* W1_1T = wt + 2 * FEAT * FEAT;
  float* W2_1T = wt + 3 * FEAT * FEAT;

  transpose4_kernel<<<4 * FEAT, FEAT, 0, stream>>>(W1_0, W2_0, W1_1, W2_1, wt);

  // zero deg + sums + slots16 in one contiguous memset (sentinel relies on it)
  hipMemsetAsync(deg, 0,
                 (size_t)(N_NODES + N_GRAPHS * FEAT + N_NODES * SLOT_MAIN) * sizeof(int),
                 stream);

  hist_place_kernel<<<NRANGE * 256, 256, 0, stream>>>(src, dst, deg, slots16, slots_ovf);

  gin_layer_kernel<false><<<512, 256, 0, stream>>>(x, deg, slots16, slots_ovf,
                                                   W1_0T, b1_0, W2_0T, b2_0,
                                                   h1, nullptr, nullptr);
  gin_layer_kernel<true><<<512, 256, 0, stream>>>(h1, deg, slots16, slots_ovf,
                                                  W1_1T, b1_1, W2_1T, b2_1,
                                                  nullptr, batch, sums);

  finish_kernel<<<N_GRAPHS, 64, 0, stream>>>(sums, batch, fcW, fcb, out);
}

// Round 11
// 418.306 us; speedup vs baseline: 1.3141x; 1.3141x over previous
//
#include <hip/hip_runtime.h>

#define N_NODES 100000
#define N_EDGES 1250000
#define FEAT 64
#define N_GRAPHS 64
#define SLOT_MAIN 16
#define SLOT_OVF 32
#define MAXDEG 48   // SLOT_MAIN + SLOT_OVF

// ---------------------------------------------------------------------------
// Build per-destination edge buckets (simple thread-per-edge; XCD-affine
// variant reverted: unvalidated, cost 8x dst reads).
// ---------------------------------------------------------------------------
__global__ void hist_place_kernel(const int* __restrict__ src,
                                  const int* __restrict__ dst,
                                  int* __restrict__ deg,
                                  int* __restrict__ slots16,
                                  int* __restrict__ slots_ovf) {
  const int e = blockIdx.x * blockDim.x + threadIdx.x;
  if (e >= N_EDGES) return;
  const int d = dst[e];
  const int pos = atomicAdd(&deg[d], 1);
  if (pos < SLOT_MAIN)      slots16[(d << 4) + pos] = src[e];
  else if (pos < MAXDEG)    slots_ovf[(size_t)d * SLOT_OVF + (pos - SLOT_MAIN)] = src[e];
}

__device__ __forceinline__ float bcast(float x, int k) {
  return __int_as_float(__builtin_amdgcn_readlane(__float_as_int(x), k));
}

// ---------------------------------------------------------------------------
// Fused GIN layer: round-8 structure widened to 4 nodes per iteration.
// Wave per node quad, lane = output feature. 68 gather loads in flight;
// MLP with 8 independent FMA chains sharing each weight value. Slot rows,
// deg and batch are wave-uniform -> scalar loads. Slots pre-zeroed ->
// unconditional tree-sum + sentinel correction (-(16-cm)*row0).
// N_NODES % 4 == 0 -> no tail handling.
// ---------------------------------------------------------------------------
template <bool POOL>
__global__ __launch_bounds__(256) void gin_layer_kernel(
    const float* __restrict__ hin,
    const int* __restrict__ deg,
    const int* __restrict__ slots16,
    const int* __restrict__ slots_ovf,
    const float* __restrict__ W1, const float* __restrict__ b1,
    const float* __restrict__ W2, const float* __restrict__ b2,
    float* __restrict__ hout,
    const int* __restrict__ batch,
    float* __restrict__ sums) {
  const int lane = threadIdx.x & 63;
  int wid = blockIdx.x * (blockDim.x >> 6) + (threadIdx.x >> 6);
  wid = __builtin_amdgcn_readfirstlane(wid);
  const int nw = gridDim.x * (blockDim.x >> 6);

  float w1[FEAT], w2[FEAT];
#pragma unroll
  for (int k = 0; k < FEAT; ++k) w1[k] = W1[k * FEAT + lane];
#pragma unroll
  for (int k = 0; k < FEAT; ++k) w2[k] = W2[k * FEAT + lane];
  const float bb1 = b1[lane];
  const float bb2 = b2[lane];
  const float r0  = hin[lane];   // sentinel row (slot 0) for zero-filled slots

  int curg = -1;
  float gacc = 0.0f;

  for (int n = wid * 4; n < N_NODES; n += nw * 4) {
    // ---- gather 4 nodes; per-q slot loads die after issuing the q's row loads
    int   cq[4], cmq[4];
    float a[4];
    float vv[4][SLOT_MAIN];
#pragma unroll
    for (int q = 0; q < 4; ++q) {
      const int nq = n + q;                       // wave-uniform
      cq[q]  = min(deg[nq], MAXDEG);              // s_load
      cmq[q] = min(cq[q], SLOT_MAIN);
      int sl[SLOT_MAIN];
#pragma unroll
      for (int i = 0; i < SLOT_MAIN; ++i) sl[i] = slots16[(nq << 4) + i];  // s_load
      a[q] = hin[((unsigned)nq << 6) + lane];
#pragma unroll
      for (int i = 0; i < SLOT_MAIN; ++i)
        vv[q][i] = hin[((unsigned)sl[i] << 6) + lane];
    }

    // ---- unconditional tree-sum + sentinel correction ----
#pragma unroll
    for (int q = 0; q < 4; ++q) {
#pragma unroll
      for (int st = 1; st < SLOT_MAIN; st <<= 1)
#pragma unroll
        for (int i = 0; i < SLOT_MAIN; i += (st << 1))
          vv[q][i] += vv[q][i + st];
      a[q] += vv[q][0];
      a[q] = fmaf((float)(cmq[q] - SLOT_MAIN), r0, a[q]);
    }

    // ---- overflow neighbors (uniform branch, ~12% of nodes) ----
#pragma unroll
    for (int q = 0; q < 4; ++q) {
      if (cq[q] > SLOT_MAIN) {
        const int* so = slots_ovf + (size_t)(n + q) * SLOT_OVF;
        for (int i = SLOT_MAIN; i < cq[q]; ++i)
          a[q] += hin[((unsigned)so[i - SLOT_MAIN] << 6) + lane];
      }
    }

    // ---- MLP layer 1: 8 chains, weights shared across the quad ----
    float h1v[4];
    {
      float acc0[4], acc1[4];
#pragma unroll
      for (int q = 0; q < 4; ++q) { acc0[q] = bb1; acc1[q] = 0.0f; }
#pragma unroll
      for (int k = 0; k < FEAT; k += 2) {
        const float wk0 = w1[k], wk1 = w1[k + 1];
#pragma unroll
        for (int q = 0; q < 4; ++q) {
          acc0[q] = fmaf(bcast(a[q], k),     wk0, acc0[q]);
          acc1[q] = fmaf(bcast(a[q], k + 1), wk1, acc1[q]);
        }
      }
#pragma unroll
      for (int q = 0; q < 4; ++q) h1v[q] = fmaxf(acc0[q] + acc1[q], 0.0f);
    }

    // ---- MLP layer 2 ----
    float h2v[4];
    {
      float acc0[4], acc1[4];
#pragma unroll
      for (int q = 0; q < 4; ++q) { acc0[q] = bb2; acc1[q] = 0.0f; }
#pragma unroll
      for (int k = 0; k < FEAT; k += 2) {
        const float wk0 = w2[k], wk1 = w2[k + 1];
#pragma unroll
        for (int q = 0; q < 4; ++q) {
          acc0[q] = fmaf(bcast(h1v[q], k),     wk0, acc0[q]);
          acc1[q] = fmaf(bcast(h1v[q], k + 1), wk1, acc1[q]);
        }
      }
#pragma unroll
      for (int q = 0; q < 4; ++q) h2v[q] = fmaxf(acc0[q] + acc1[q], 0.0f);
    }

    // ---- output ----
    if (POOL) {
#pragma unroll
      for (int q = 0; q < 4; ++q) {
        const int g = batch[n + q];               // s_load, wave-uniform
        if (g != curg) {
          if (curg >= 0) atomicAdd(&sums[curg * FEAT + lane], gacc);
          curg = g; gacc = 0.0f;
        }
        gacc += h2v[q];
      }
    } else {
#pragma unroll
      for (int q = 0; q < 4; ++q)
        hout[((unsigned)(n + q) << 6) + lane] = h2v[q];
    }
  }
  if (POOL && curg >= 0) atomicAdd(&sums[curg * FEAT + lane], gacc);
}

// ---------------------------------------------------------------------------
// out[g] = dot(sums[g,:], fcW) / cnt[g] + fcb; cnt via binary search on the
// sorted batch array.
// ---------------------------------------------------------------------------
__device__ __forceinline__ int lower_bound_dev(const int* __restrict__ a,
                                               int n, int key) {
  int lo = 0, hi = n;
  while (lo < hi) {
    const int mid = (lo + hi) >> 1;
    if (a[mid] < key) lo = mid + 1; else hi = mid;
  }
  return lo;
}

__global__ void finish_kernel(const float* __restrict__ sums,
                              const int* __restrict__ batch,
                              const float* __restrict__ fcW,
                              const float* __restrict__ fcb,
                              float* __restrict__ out) {
  const int g = blockIdx.x;
  const int lane = threadIdx.x;

  int cnt = 0;
  if (lane == 0) {
    const int lo = lower_bound_dev(batch, N_NODES, g);
    const int hi = lower_bound_dev(batch, N_NODES, g + 1);
    cnt = hi - lo;
  }
  cnt = __shfl(cnt, 0);

  float v = sums[g * FEAT + lane] * fcW[lane];
#pragma unroll
  for (int off = 32; off > 0; off >>= 1) v += __shfl_down(v, off);
  if (lane == 0) out[g] = v / fmaxf((float)cnt, 1.0f) + fcb[0];
}

extern "C" void kernel_launch(void* const* d_in, const int* in_sizes, int n_in,
                              void* d_out, int out_size, void* d_ws, size_t ws_size,
                              hipStream_t stream) {
  const float* x     = (const float*)d_in[0];
  const int*   ei    = (const int*)d_in[1];
  const int*   batch = (const int*)d_in[2];
  const float* W1_0  = (const float*)d_in[3];
  const float* b1_0  = (const float*)d_in[4];
  const float* W2_0  = (const float*)d_in[5];
  const float* b2_0  = (const float*)d_in[6];
  const float* W1_1  = (const float*)d_in[7];
  const float* b1_1  = (const float*)d_in[8];
  const float* W2_1  = (const float*)d_in[9];
  const float* b2_1  = (const float*)d_in[10];
  const float* fcW   = (const float*)d_in[11];
  const float* fcb   = (const float*)d_in[12];
  float* out = (float*)d_out;

  const int* src = ei;            // edge_index[0]
  const int* dst = ei + N_EDGES;  // edge_index[1]

  // workspace layout: [deg | sums | slots16 | slots_ovf | h1]
  int*   deg       = (int*)d_ws;                            // N_NODES
  float* sums      = (float*)(deg + N_NODES);               // N_GRAPHS*FEAT
  int*   slots16   = (int*)(sums + N_GRAPHS * FEAT);        // N_NODES*16
  int*   slots_ovf = slots16 + (size_t)N_NODES * SLOT_MAIN; // N_NODES*32
  float* h1        = (float*)(slots_ovf + (size_t)N_NODES * SLOT_OVF); // N_NODES*FEAT

  // zero deg + sums + slots16 in one contiguous memset (sentinel relies on it)
  hipMemsetAsync(deg, 0,
                 (size_t)(N_NODES + N_GRAPHS * FEAT + N_NODES * SLOT_MAIN) * sizeof(int),
                 stream);

  hist_place_kernel<<<(N_EDGES + 255) / 256, 256, 0, stream>>>(src, dst, deg,
                                                               slots16, slots_ovf);

  gin_layer_kernel<false><<<2048, 256, 0, stream>>>(x, deg, slots16, slots_ovf,
                                                    W1_0, b1_0, W2_0, b2_0,
                                                    h1, nullptr, nullptr);
  gin_layer_kernel<true><<<2048, 256, 0, stream>>>(h1, deg, slots16, slots_ovf,
                                                   W1_1, b1_1, W2_1, b2_1,
                                                   nullptr, batch, sums);

  finish_kernel<<<N_GRAPHS, 64, 0, stream>>>(sums, batch, fcW, fcb, out);
}